// Round 8
// baseline (9525.398 us; speedup 1.0000x reference)
//
#include <hip/hip_runtime.h>
#include <stdint.h>

typedef __attribute__((ext_vector_type(4))) float f32x4;
typedef __attribute__((ext_vector_type(8))) short s16x8;
typedef __attribute__((ext_vector_type(4))) unsigned short u16x4;
typedef __attribute__((ext_vector_type(4))) unsigned int u32x4;

#define T_SEQ 1024
#define HID 512

__device__ __forceinline__ unsigned short f2bf(float f) {
  uint32_t u = __float_as_uint(f);
  u += 0x7fffu + ((u >> 16) & 1u);  // round-to-nearest-even
  return (unsigned short)(u >> 16);
}
__device__ __forceinline__ float sigf(float x) { return 1.f / (1.f + __expf(-x)); }
__device__ __forceinline__ float tanhfast(float x) {
  float e = __expf(2.f * x);
  return (e - 1.f) / (e + 1.f);
}

#define ASTORE(p, v) __hip_atomic_store((p), (v), __ATOMIC_RELAXED, __HIP_MEMORY_SCOPE_AGENT)
#define MFMA(a, b, c) __builtin_amdgcn_mfma_f32_16x16x32_bf16((a), (b), (c), 0, 0, 0)

// Coherence-point 16B load (sc0 sc1) — proven r4/r7. sc0-alone is L1-hittable (r6 bug).
__device__ __forceinline__ u32x4 load_coh16(const unsigned int* p) {
  u32x4 r;
  asm volatile("global_load_dwordx4 %0, %1, off sc0 sc1" : "=v"(r) : "v"(p) : "memory");
  return r;
}
#define VM_WAIT0 do { asm volatile("s_waitcnt vmcnt(0)" ::: "memory"); \
                      __builtin_amdgcn_sched_barrier(0); } while (0)
#define VM_WAIT4 do { asm volatile("s_waitcnt vmcnt(4)" ::: "memory"); \
                      __builtin_amdgcn_sched_barrier(0); } while (0)
#define LGKM0 do { asm volatile("s_waitcnt lgkmcnt(0)" ::: "memory"); } while (0)

// bounded LDS flag spin (monotone counters; bound = fail-fast insurance, never hangs)
__device__ __forceinline__ void lds_wait(volatile int* f, int target) {
  int it = 0;
  while (*f < target) {
    if (++it > (1 << 18)) break;
    __builtin_amdgcn_s_sleep(1);
  }
  asm volatile("" ::: "memory");  // no hoisting of data reads above the spin
}

__device__ __forceinline__ u32x4 pack2(const u32x4 a, const u32x4 b) {
  return u32x4{(a[0] & 0xffffu) | (a[1] << 16), (a[2] & 0xffffu) | (a[3] << 16),
               (b[0] & 0xffffu) | (b[1] << 16), (b[2] & 0xffffu) | (b[3] << 16)};
}

#define GLL(gp, lp)                                                      \
  __builtin_amdgcn_global_load_lds(                                     \
      (const __attribute__((address_space(1))) void*)(gp),              \
      (__attribute__((address_space(3))) void*)(lp), 16, 0, 0)

// ---------------- small prep kernels ----------------
__global__ __launch_bounds__(256) void embed_kernel(const int* __restrict__ inp,
                                                    const float* __restrict__ wte,
                                                    unsigned short* __restrict__ xbf) {
  const int m = blockIdx.x;  // m = b*1024 + t
  const int idx = inp[m];
  const float* src = wte + (size_t)idx * HID;
  unsigned short* dst = xbf + (size_t)m * HID;
  const int e = threadIdx.x;
  dst[e] = f2bf(src[e]);
  dst[e + 256] = f2bf(src[e + 256]);
}

__global__ __launch_bounds__(256) void cvt_bf16_kernel(const float* __restrict__ src,
                                                       unsigned short* __restrict__ dst,
                                                       int n4) {
  const int i = blockIdx.x * 256 + threadIdx.x;
  if (i >= n4) return;
  f32x4 v = ((const f32x4*)src)[i];
  u16x4 o;
  o.x = f2bf(v.x); o.y = f2bf(v.y); o.z = f2bf(v.z); o.w = f2bf(v.w);
  ((u16x4*)dst)[i] = o;
}

__global__ __launch_bounds__(256) void bias_sum_kernel(const float* __restrict__ a,
                                                       const float* __restrict__ b,
                                                       float* __restrict__ o, int n) {
  const int i = blockIdx.x * 256 + threadIdx.x;
  if (i < n) o[i] = a[i] + b[i];
}

// ---------------- bf16 MFMA GEMM:  C[m][n] = sum_k A[m][k]*B[n][k] + bias[n] ----------------
// MODE 0: C row = m. MODE 1: m = t*8+b -> C row = b*1024+t. MODE 2: m = b*1024+t -> row = t*8+b.
template <int MODE>
__global__ __launch_bounds__(256) void gemm_bt(const unsigned short* __restrict__ A,
                                               const unsigned short* __restrict__ B,
                                               float* __restrict__ C,
                                               const float* __restrict__ bias,
                                               int M, int N, int K) {
  __shared__ unsigned short As[128 * 32];
  __shared__ unsigned short Bs[128 * 32];
  const int nTiles = N >> 7;
  const int mt = blockIdx.x / nTiles;
  const int nt = blockIdx.x - mt * nTiles;
  const int m0 = mt << 7, n0 = nt << 7;
  const int tid = threadIdx.x;
  const int wave = tid >> 6, lane = tid & 63;
  const int wm = wave >> 1, wn = wave & 1;

  const int c1 = wave * 64 + lane;
  const int c2 = 256 + c1;
  const unsigned short* gA1 = A + (size_t)(m0 + (c1 >> 2)) * K + (c1 & 3) * 8;
  const unsigned short* gA2 = A + (size_t)(m0 + (c2 >> 2)) * K + (c2 & 3) * 8;
  const unsigned short* gB1 = B + (size_t)(n0 + (c1 >> 2)) * K + (c1 & 3) * 8;
  const unsigned short* gB2 = B + (size_t)(n0 + (c2 >> 2)) * K + (c2 & 3) * 8;
  unsigned short* lA1 = As + wave * 512;
  unsigned short* lA2 = As + 2048 + wave * 512;
  unsigned short* lB1 = Bs + wave * 512;
  unsigned short* lB2 = Bs + 2048 + wave * 512;

  f32x4 acc[4][4] = {};
  const int row_lo = lane & 15;
  const int kq = (lane >> 4) * 8;

  for (int k0 = 0; k0 < K; k0 += 32) {
    GLL(gA1 + k0, lA1);
    GLL(gA2 + k0, lA2);
    GLL(gB1 + k0, lB1);
    GLL(gB2 + k0, lB2);
    __syncthreads();
    s16x8 af[4], bfr[4];
#pragma unroll
    for (int f = 0; f < 4; ++f) {
      af[f] = *(const s16x8*)(As + (wm * 64 + f * 16 + row_lo) * 32 + kq);
      bfr[f] = *(const s16x8*)(Bs + (wn * 64 + f * 16 + row_lo) * 32 + kq);
    }
#pragma unroll
    for (int i = 0; i < 4; ++i)
#pragma unroll
      for (int j = 0; j < 4; ++j)
        acc[i][j] = MFMA(af[i], bfr[j], acc[i][j]);
    __syncthreads();
  }

  float bv[4];
#pragma unroll
  for (int j = 0; j < 4; ++j) bv[j] = bias[n0 + wn * 64 + j * 16 + row_lo];
  const int rbase = (lane >> 4) * 4;
#pragma unroll
  for (int i = 0; i < 4; ++i) {
#pragma unroll
    for (int r = 0; r < 4; ++r) {
      const int m = m0 + wm * 64 + i * 16 + rbase + r;
      const size_t row = MODE == 1 ? ((size_t)(m & 7) * T_SEQ + (m >> 3))
                       : MODE == 2 ? ((size_t)(m & (T_SEQ - 1)) * 8 + (m >> 10))
                                   : (size_t)m;
      float* cp = C + row * (size_t)N;
#pragma unroll
      for (int j = 0; j < 4; ++j) cp[n0 + wn * 64 + j * 16 + row_lo] = acc[i][j][r] + bv[j];
    }
  }
}

// ---------------- persistent 2-layer LSTM, wave-specialized ----------------
// 32 WGs x 4 waves. Two independent 2-wave engines per WG (no __syncthreads in loop):
//   L1: wave0 = poll/stage h1(t-1)+xg, MFMA g01 ; wave1 = MFMA g23, pointwise, ALL stores
//       (wave1 never executes a vmem wait -> store drain off the critical path).
//   L2: wave2 = poll/stage h2(s-1), MFMA g01 ; wave3 = stage h1(s) (loads issued BEFORE its
//       stores, completed with counted vmcnt(4)), MFMA g23, pointwise, stores.
// Sync: tagged u32 (bf16 | (step+1)<<16), relaxed-agent stores, sc0+sc1 polls (proven r4/r7).
// Intra-WG: monotone LDS flags (lgkmcnt(0) before set, memory clobber after spin, bounded).
__global__ __launch_bounds__(256, 1) void lstm_ws(
    const float* __restrict__ xg1t,            // [t*8+b][2048]
    const unsigned short* __restrict__ whh1,
    const unsigned short* __restrict__ wih2,
    const unsigned short* __restrict__ whh2,
    const float* __restrict__ bias2,           // b_ih+b_hh layer 2
    unsigned int* __restrict__ h1T,            // [t][8][512] tagged u32
    unsigned int* __restrict__ h2T,            // [t][8][512] tagged u32
    unsigned short* __restrict__ h2out) {      // [t*8+b][512] bf16 (FC input)
  __shared__ __align__(16) char t1[2][8192];   // h1 tile (L1 engine), parity
  __shared__ __align__(16) char t1b[2][8192];  // h1 tile (L2 engine), parity
  __shared__ __align__(16) char t2[2][8192];   // h2 tile, parity
  __shared__ float GT1[2][512];                // [gate][unit16][batch8]
  __shared__ float GT2[2][512];
  __shared__ float XG[2][512];                 // [gate][batch8][unit16]
  __shared__ int F[8];                         // 0:fS1 1:fG1 2:fS2 3:fG2 4:fH1

  const int tid = threadIdx.x, wave = tid >> 6, l = tid & 63;
  const int wg = blockIdx.x, u0 = wg * 16;
  const int unit = l & 15, grp = l >> 4;
  const int row = l & 7;        // A-frag row / staging batch row
  const int c64 = l >> 3;       // staging column block (64 u32)
  volatile int* vF = F;

  if (tid < 8) F[tid] = 0;
  __syncthreads();  // the only whole-WG barrier

  if (wave == 0) {
    // ================= L1 poller/stager + MFMA gates 0,1 =================
    s16x8 bf[2][16];
#pragma unroll
    for (int gi = 0; gi < 2; ++gi) {
      const size_t grow = (size_t)(gi * 512 + u0 + unit) * 512;
#pragma unroll
      for (int kt = 0; kt < 16; ++kt)
        bf[gi][kt] = *(const s16x8*)(whh1 + grow + kt * 32 + grp * 8);
    }
    const int xb = (l >> 1) & 7, xg_ = l >> 4, xh = l & 1;  // xg lane mapping
    for (int t = 0; t < T_SEQ; ++t) {
      const int par = t & 1;
      // coalesced xg loads (plain; static data)
      const float* xs = xg1t + ((size_t)t * 8 + xb) * 2048 + xg_ * 512 + u0 + xh * 8;
      f32x4 xa = *(const f32x4*)xs;
      f32x4 xc = *(const f32x4*)(xs + 4);
      char* dst = t1[par];
      if (t > 0) {
        const unsigned int* src = h1T + (size_t)(t - 1) * 4096 + row * 512 + c64 * 64;
        const unsigned int tg = (unsigned int)t;
        u32x4 d[16];
        int spin = 0;
        for (;;) {
#pragma unroll
          for (int j = 0; j < 16; ++j) d[j] = load_coh16(src + j * 4);
          VM_WAIT0;
          bool ok = true;
#pragma unroll
          for (int j = 0; j < 16; ++j)
#pragma unroll
            for (int k = 0; k < 4; ++k) ok &= (d[j][k] >> 16) == tg;
          if (__ballot(ok) == ~0ULL) break;
          if (++spin > (1 << 12)) break;  // fail-fast insurance
          __builtin_amdgcn_s_sleep(1);
        }
#pragma unroll
        for (int j2 = 0; j2 < 8; ++j2)
          *(u32x4*)(dst + ((row * 1024 + c64 * 128 + j2 * 16) ^ (row << 4))) =
              pack2(d[j2 * 2], d[j2 * 2 + 1]);
      } else {
#pragma unroll
        for (int j2 = 0; j2 < 8; ++j2)
          *(u32x4*)(dst + ((row * 1024 + c64 * 128 + j2 * 16) ^ (row << 4))) = u32x4{0, 0, 0, 0};
      }
      float* xgd = &XG[par][xg_ * 128 + xb * 16 + xh * 8];
      *(f32x4*)xgd = xa;
      *(f32x4*)(xgd + 4) = xc;
      LGKM0;
      vF[0] = t + 1;  // staging done
      // MFMA gates 0,1
      const char* hb = t1[par];
#pragma unroll
      for (int gi = 0; gi < 2; ++gi) {
        f32x4 q0 = {}, q1 = {}, q2 = {}, q3 = {};
#pragma unroll
        for (int kt = 0; kt < 16; kt += 4) {
          s16x8 x0 = *(const s16x8*)(hb + ((row * 1024 + (kt + 0) * 64 + grp * 16) ^ (row << 4)));
          s16x8 x1 = *(const s16x8*)(hb + ((row * 1024 + (kt + 1) * 64 + grp * 16) ^ (row << 4)));
          s16x8 x2 = *(const s16x8*)(hb + ((row * 1024 + (kt + 2) * 64 + grp * 16) ^ (row << 4)));
          s16x8 x3 = *(const s16x8*)(hb + ((row * 1024 + (kt + 3) * 64 + grp * 16) ^ (row << 4)));
          q0 = MFMA(x0, bf[gi][kt + 0], q0);
          q1 = MFMA(x1, bf[gi][kt + 1], q1);
          q2 = MFMA(x2, bf[gi][kt + 2], q2);
          q3 = MFMA(x3, bf[gi][kt + 3], q3);
        }
        f32x4 acc = (q0 + q1) + (q2 + q3);
        if (grp < 2) *(f32x4*)(&GT1[par][gi * 128 + unit * 8 + grp * 4]) = acc;
      }
      LGKM0;
      vF[1] = t + 1;  // GT1 half g0,g1 done
    }
  } else if (wave == 1) {
    // ================= L1 MFMA gates 2,3 + pointwise + stores (never waits vmem) ==========
    s16x8 bf[2][16];
#pragma unroll
    for (int gi = 0; gi < 2; ++gi) {
      const size_t grow = (size_t)((2 + gi) * 512 + u0 + unit) * 512;
#pragma unroll
      for (int kt = 0; kt < 16; ++kt)
        bf[gi][kt] = *(const s16x8*)(whh1 + grow + kt * 32 + grp * 8);
    }
    const int pb = l & 7, pu = l >> 3;
    float cst[2] = {0.f, 0.f};
    for (int t = 0; t < T_SEQ; ++t) {
      const int par = t & 1;
      lds_wait(&vF[0], t + 1);
      const char* hb = t1[par];
#pragma unroll
      for (int gi = 0; gi < 2; ++gi) {
        f32x4 q0 = {}, q1 = {}, q2 = {}, q3 = {};
#pragma unroll
        for (int kt = 0; kt < 16; kt += 4) {
          s16x8 x0 = *(const s16x8*)(hb + ((row * 1024 + (kt + 0) * 64 + grp * 16) ^ (row << 4)));
          s16x8 x1 = *(const s16x8*)(hb + ((row * 1024 + (kt + 1) * 64 + grp * 16) ^ (row << 4)));
          s16x8 x2 = *(const s16x8*)(hb + ((row * 1024 + (kt + 2) * 64 + grp * 16) ^ (row << 4)));
          s16x8 x3 = *(const s16x8*)(hb + ((row * 1024 + (kt + 3) * 64 + grp * 16) ^ (row << 4)));
          q0 = MFMA(x0, bf[gi][kt + 0], q0);
          q1 = MFMA(x1, bf[gi][kt + 1], q1);
          q2 = MFMA(x2, bf[gi][kt + 2], q2);
          q3 = MFMA(x3, bf[gi][kt + 3], q3);
        }
        f32x4 acc = (q0 + q1) + (q2 + q3);
        if (grp < 2) *(f32x4*)(&GT1[par][(2 + gi) * 128 + unit * 8 + grp * 4]) = acc;
      }
      lds_wait(&vF[1], t + 1);  // wave0's GT half (own half ordered by compiler lgkm)
#pragma unroll
      for (int r = 0; r < 2; ++r) {
        const int u = r * 8 + pu;
        float gi = GT1[par][0 + u * 8 + pb] + XG[par][0 + pb * 16 + u];
        float gf = GT1[par][128 + u * 8 + pb] + XG[par][128 + pb * 16 + u];
        float gv = GT1[par][256 + u * 8 + pb] + XG[par][256 + pb * 16 + u];
        float go = GT1[par][384 + u * 8 + pb] + XG[par][384 + pb * 16 + u];
        cst[r] = sigf(gf) * cst[r] + sigf(gi) * tanhfast(gv);
        const float hv = sigf(go) * tanhfast(cst[r]);
        ASTORE(h1T + (size_t)t * 4096 + pb * 512 + u0 + u,
               (unsigned int)f2bf(hv) | ((unsigned int)(t + 1) << 16));
      }
    }
  } else if (wave == 2) {
    // ================= L2 poller/stager (h2) + MFMA gates 0,1 =================
    s16x8 bi[2][16], bh[2][16];
#pragma unroll
    for (int gi = 0; gi < 2; ++gi) {
      const size_t grow = (size_t)(gi * 512 + u0 + unit) * 512;
#pragma unroll
      for (int kt = 0; kt < 16; ++kt) {
        bi[gi][kt] = *(const s16x8*)(wih2 + grow + kt * 32 + grp * 8);
        bh[gi][kt] = *(const s16x8*)(whh2 + grow + kt * 32 + grp * 8);
      }
    }
    for (int s = 0; s < T_SEQ; ++s) {
      const int par = s & 1;
      char* dst = t2[par];
      if (s > 0) {
        const unsigned int* src = h2T + (size_t)(s - 1) * 4096 + row * 512 + c64 * 64;
        const unsigned int tg = (unsigned int)s;
        u32x4 d[16];
        int spin = 0;
        for (;;) {
#pragma unroll
          for (int j = 0; j < 16; ++j) d[j] = load_coh16(src + j * 4);
          VM_WAIT0;
          bool ok = true;
#pragma unroll
          for (int j = 0; j < 16; ++j)
#pragma unroll
            for (int k = 0; k < 4; ++k) ok &= (d[j][k] >> 16) == tg;
          if (__ballot(ok) == ~0ULL) break;
          if (++spin > (1 << 12)) break;
          __builtin_amdgcn_s_sleep(1);
        }
#pragma unroll
        for (int j2 = 0; j2 < 8; ++j2)
          *(u32x4*)(dst + ((row * 1024 + c64 * 128 + j2 * 16) ^ (row << 4))) =
              pack2(d[j2 * 2], d[j2 * 2 + 1]);
      } else {
#pragma unroll
        for (int j2 = 0; j2 < 8; ++j2)
          *(u32x4*)(dst + ((row * 1024 + c64 * 128 + j2 * 16) ^ (row << 4))) = u32x4{0, 0, 0, 0};
      }
      LGKM0;
      vF[2] = s + 1;
      lds_wait(&vF[4], s + 1);  // h1(s) staged by wave3
      const char* ha = t1b[par];
      const char* hc = t2[par];
#pragma unroll
      for (int gi = 0; gi < 2; ++gi) {
        f32x4 q0 = {}, q1 = {}, q2 = {}, q3 = {};
#pragma unroll
        for (int kt = 0; kt < 16; kt += 4) {
          s16x8 x0 = *(const s16x8*)(ha + ((row * 1024 + (kt + 0) * 64 + grp * 16) ^ (row << 4)));
          s16x8 x1 = *(const s16x8*)(ha + ((row * 1024 + (kt + 1) * 64 + grp * 16) ^ (row << 4)));
          s16x8 x2 = *(const s16x8*)(ha + ((row * 1024 + (kt + 2) * 64 + grp * 16) ^ (row << 4)));
          s16x8 x3 = *(const s16x8*)(ha + ((row * 1024 + (kt + 3) * 64 + grp * 16) ^ (row << 4)));
          q0 = MFMA(x0, bi[gi][kt + 0], q0);
          q1 = MFMA(x1, bi[gi][kt + 1], q1);
          q2 = MFMA(x2, bi[gi][kt + 2], q2);
          q3 = MFMA(x3, bi[gi][kt + 3], q3);
        }
#pragma unroll
        for (int kt = 0; kt < 16; kt += 4) {
          s16x8 x0 = *(const s16x8*)(hc + ((row * 1024 + (kt + 0) * 64 + grp * 16) ^ (row << 4)));
          s16x8 x1 = *(const s16x8*)(hc + ((row * 1024 + (kt + 1) * 64 + grp * 16) ^ (row << 4)));
          s16x8 x2 = *(const s16x8*)(hc + ((row * 1024 + (kt + 2) * 64 + grp * 16) ^ (row << 4)));
          s16x8 x3 = *(const s16x8*)(hc + ((row * 1024 + (kt + 3) * 64 + grp * 16) ^ (row << 4)));
          q0 = MFMA(x0, bh[gi][kt + 0], q0);
          q1 = MFMA(x1, bh[gi][kt + 1], q1);
          q2 = MFMA(x2, bh[gi][kt + 2], q2);
          q3 = MFMA(x3, bh[gi][kt + 3], q3);
        }
        f32x4 acc = (q0 + q1) + (q2 + q3);
        if (grp < 2) *(f32x4*)(&GT2[par][gi * 128 + unit * 8 + grp * 4]) = acc;
      }
      LGKM0;
      vF[3] = s + 1;
    }
  } else {
    // ================= L2 h1-stager + MFMA gates 2,3 + pointwise + stores =================
    s16x8 bi[2][16], bh[2][16];
#pragma unroll
    for (int gi = 0; gi < 2; ++gi) {
      const size_t grow = (size_t)((2 + gi) * 512 + u0 + unit) * 512;
#pragma unroll
      for (int kt = 0; kt < 16; ++kt) {
        bi[gi][kt] = *(const s16x8*)(wih2 + grow + kt * 32 + grp * 8);
        bh[gi][kt] = *(const s16x8*)(whh2 + grow + kt * 32 + grp * 8);
      }
    }
    const int pb = l & 7, pu = l >> 3;
    float bias_g[2][4];
#pragma unroll
    for (int r = 0; r < 2; ++r)
#pragma unroll
      for (int g = 0; g < 4; ++g) bias_g[r][g] = bias2[g * 512 + u0 + r * 8 + pu];
    float cst[2] = {0.f, 0.f};
    u32x4 pre[16];
    {  // prologue: issue h1(0) loads (no stores outstanding yet)
      const unsigned int* src = h1T + row * 512 + c64 * 64;
#pragma unroll
      for (int j = 0; j < 16; ++j) pre[j] = load_coh16(src + j * 4);
    }
    for (int s = 0; s < T_SEQ; ++s) {
      const int par = s & 1;
      // finish h1(s) staging: loads were issued BEFORE this wave's stores -> counted wait
      if (s == 0) { VM_WAIT0; } else { VM_WAIT4; }  // 4 newest = my stores, stay in flight
      const unsigned int tg1 = (unsigned int)(s + 1);
      bool ok = true;
#pragma unroll
      for (int j = 0; j < 16; ++j)
#pragma unroll
        for (int k = 0; k < 4; ++k) ok &= (pre[j][k] >> 16) == tg1;
      if (__ballot(ok) != ~0ULL) {  // rare: h1(s) not yet visible -> coherent retry
        const unsigned int* src = h1T + (size_t)s * 4096 + row * 512 + c64 * 64;
        int spin = 0;
        for (;;) {
#pragma unroll
          for (int j = 0; j < 16; ++j) pre[j] = load_coh16(src + j * 4);
          VM_WAIT0;
          ok = true;
#pragma unroll
          for (int j = 0; j < 16; ++j)
#pragma unroll
            for (int k = 0; k < 4; ++k) ok &= (pre[j][k] >> 16) == tg1;
          if (__ballot(ok) == ~0ULL) break;
          if (++spin > (1 << 12)) break;
          __builtin_amdgcn_s_sleep(1);
        }
      }
      char* dst = t1b[par];
#pragma unroll
      for (int j2 = 0; j2 < 8; ++j2)
        *(u32x4*)(dst + ((row * 1024 + c64 * 128 + j2 * 16) ^ (row << 4))) =
            pack2(pre[j2 * 2], pre[j2 * 2 + 1]);
      LGKM0;
      vF[4] = s + 1;
      lds_wait(&vF[2], s + 1);  // h2 tile staged by wave2
      const char* ha = t1b[par];
      const char* hc = t2[par];
#pragma unroll
      for (int gi = 0; gi < 2; ++gi) {
        f32x4 q0 = {}, q1 = {}, q2 = {}, q3 = {};
#pragma unroll
        for (int kt = 0; kt < 16; kt += 4) {
          s16x8 x0 = *(const s16x8*)(ha + ((row * 1024 + (kt + 0) * 64 + grp * 16) ^ (row << 4)));
          s16x8 x1 = *(const s16x8*)(ha + ((row * 1024 + (kt + 1) * 64 + grp * 16) ^ (row << 4)));
          s16x8 x2 = *(const s16x8*)(ha + ((row * 1024 + (kt + 2) * 64 + grp * 16) ^ (row << 4)));
          s16x8 x3 = *(const s16x8*)(ha + ((row * 1024 + (kt + 3) * 64 + grp * 16) ^ (row << 4)));
          q0 = MFMA(x0, bi[gi][kt + 0], q0);
          q1 = MFMA(x1, bi[gi][kt + 1], q1);
          q2 = MFMA(x2, bi[gi][kt + 2], q2);
          q3 = MFMA(x3, bi[gi][kt + 3], q3);
        }
#pragma unroll
        for (int kt = 0; kt < 16; kt += 4) {
          s16x8 x0 = *(const s16x8*)(hc + ((row * 1024 + (kt + 0) * 64 + grp * 16) ^ (row << 4)));
          s16x8 x1 = *(const s16x8*)(hc + ((row * 1024 + (kt + 1) * 64 + grp * 16) ^ (row << 4)));
          s16x8 x2 = *(const s16x8*)(hc + ((row * 1024 + (kt + 2) * 64 + grp * 16) ^ (row << 4)));
          s16x8 x3 = *(const s16x8*)(hc + ((row * 1024 + (kt + 3) * 64 + grp * 16) ^ (row << 4)));
          q0 = MFMA(x0, bh[gi][kt + 0], q0);
          q1 = MFMA(x1, bh[gi][kt + 1], q1);
          q2 = MFMA(x2, bh[gi][kt + 2], q2);
          q3 = MFMA(x3, bh[gi][kt + 3], q3);
        }
        f32x4 acc = (q0 + q1) + (q2 + q3);
        if (grp < 2) *(f32x4*)(&GT2[par][(2 + gi) * 128 + unit * 8 + grp * 4]) = acc;
      }
      // issue NEXT step's h1 loads before this step's stores (keeps vmcnt FIFO store-last)
      if (s + 1 < T_SEQ) {
        const unsigned int* src = h1T + (size_t)(s + 1) * 4096 + row * 512 + c64 * 64;
#pragma unroll
        for (int j = 0; j < 16; ++j) pre[j] = load_coh16(src + j * 4);
      }
      lds_wait(&vF[3], s + 1);  // wave2's GT half
#pragma unroll
      for (int r = 0; r < 2; ++r) {
        const int u = r * 8 + pu;
        float gi = GT2[par][0 + u * 8 + pb] + bias_g[r][0];
        float gf = GT2[par][128 + u * 8 + pb] + bias_g[r][1];
        float gv = GT2[par][256 + u * 8 + pb] + bias_g[r][2];
        float go = GT2[par][384 + u * 8 + pb] + bias_g[r][3];
        cst[r] = sigf(gf) * cst[r] + sigf(gi) * tanhfast(gv);
        const float hv = sigf(go) * tanhfast(cst[r]);
        const unsigned int hb16 = f2bf(hv);
        ASTORE(h2T + (size_t)s * 4096 + pb * 512 + u0 + u,
               hb16 | ((unsigned int)(s + 1) << 16));
        h2out[((size_t)s * 8 + pb) * 512 + u0 + u] = (unsigned short)hb16;
      }
    }
  }
}

// ---------------- host launch ----------------
extern "C" void kernel_launch(void* const* d_in, const int* in_sizes, int n_in,
                              void* d_out, int out_size, void* d_ws, size_t ws_size,
                              hipStream_t stream) {
  (void)in_sizes; (void)n_in; (void)out_size; (void)ws_size;
  const int* inp = (const int*)d_in[0];
  const float* wte = (const float*)d_in[1];
  const float* W_ih = (const float*)d_in[2];
  const float* W_hh = (const float*)d_in[3];
  const float* b_ih = (const float*)d_in[4];
  const float* b_hh = (const float*)d_in[5];
  const float* fc_w = (const float*)d_in[6];
  const float* fc_b = (const float*)d_in[7];
  float* out = (float*)d_out;

  // Large intermediates inside d_out (1 GB; fully overwritten by the final FC GEMM).
  char* ob = (char*)d_out;
  float* xg1t = (float*)(ob);                                    // [  0, 64M) [t*8+b][2048]
  unsigned int* h1T = (unsigned int*)(ob + (64u << 20));         // [ 64, 80M) tagged u32
  unsigned int* h2T = (unsigned int*)(ob + (80u << 20));         // [ 80, 96M) tagged u32
  unsigned short* x_bf = (unsigned short*)(ob + (96u << 20));    // [ 96,104M)
  unsigned short* whh_bf = (unsigned short*)(ob + (104u << 20)); // [104,108M)
  unsigned short* wih_bf = (unsigned short*)(ob + (108u << 20)); // [108,112M)

  char* ws = (char*)d_ws;  // within proven 43 MiB footprint
  unsigned short* fcw_bf = (unsigned short*)(ws);                // [ 0,32M)
  float* bias12 = (float*)(ws + (32u << 20));                    // 16 KiB
  unsigned short* h2bf = (unsigned short*)(ws + (35u << 20));    // [35,43M) [t*8+b][512]

  hipMemsetAsync(ob + (64u << 20), 0, 32u << 20, stream);  // clear h tags (honest sync/replay)
  embed_kernel<<<8192, 256, 0, stream>>>(inp, wte, x_bf);
  cvt_bf16_kernel<<<2048, 256, 0, stream>>>(W_ih, wih_bf, 2 * 2048 * 512 / 4);
  cvt_bf16_kernel<<<2048, 256, 0, stream>>>(W_hh, whh_bf, 2 * 2048 * 512 / 4);
  cvt_bf16_kernel<<<16000, 256, 0, stream>>>(fc_w, fcw_bf, 32000 * 512 / 4);
  bias_sum_kernel<<<16, 256, 0, stream>>>(b_ih, b_hh, bias12, 4096);
  // xg1t[t*8+b][g] = x @ W_ih0^T + (b_ih0 + b_hh0)
  gemm_bt<2><<<64 * 16, 256, 0, stream>>>(x_bf, wih_bf, xg1t, bias12, 8192, 2048, 512);
  lstm_ws<<<32, 256, 0, stream>>>(xg1t, whh_bf, wih_bf + (size_t)2048 * 512,
                                  whh_bf + (size_t)2048 * 512, bias12 + 2048,
                                  h1T, h2T, h2bf);
  // logits = h2 @ fc_w^T + fc_b  (A rows t*8+b -> C rows b*1024+t)
  gemm_bt<1><<<64 * 250, 256, 0, stream>>>(h2bf, fcw_bf, out, fc_b, 8192, 32000, 512);
}